// Round 8
// baseline (86.623 us; speedup 1.0000x reference)
//
#include <hip/hip_runtime.h>
#include <math.h>

#define SEQ 4096
#define NH  8
#define DIM 64
// 32 (n,h) pairs total: n=4, h=8

__device__ __forceinline__ float elu1(float x) {
    // jax.nn.elu(x)+1: branchless — exp(min(x,0)) + max(x,0)
    return __expf(fminf(x, 0.0f)) + fmaxf(x, 0.0f);
}

// ---------------- Phase 1: partial KV (64x64) + partial Ksum per (n,h,chunk) ----------------
// h-FUSED streaming (R7) + DISTANCE-4 software pipeline (this round).
// R7 was latency-bound: 2 waves/SIMD with distance-1 prefetch exposed
// ~400+ cyc of memory latency per row iteration (VALUBusy 36%, warm BW
// 670 GB/s at same dur as cold 1340 -> not BW-bound). Four NAMED row
// buffers (no runtime indexing -> no scratch), modulo-4 unrolled loop:
// compute row s from buf i, immediately re-issue buf i's loads for s+4.
// Steady state: 16 loads/wave in flight ~= 680 cyc cover, x2 waves/SIMD.
#define ROW_LOAD(B, sidx) do {                                   \
    const float* kr_ = Kp + (size_t)(sidx) * (NH * DIM);         \
    const float* vr_ = Vp + (size_t)(sidx) * (NH * DIM);         \
    B##ka = *(const float4*)(kr_ + d0);                          \
    B##kb = *(const float4*)(kr_ + d0 + 4);                      \
    B##va = *(const float4*)(vr_ + v0);                          \
    B##vb = *(const float4*)(vr_ + v0 + 4);                      \
} while (0)

#define ROW_COMPUTE(B) do {                                               \
    float a_[8] = {elu1(B##ka.x), elu1(B##ka.y), elu1(B##ka.z),           \
                   elu1(B##ka.w), elu1(B##kb.x), elu1(B##kb.y),           \
                   elu1(B##kb.z), elu1(B##kb.w)};                         \
    float b_[8] = {B##va.x, B##va.y, B##va.z, B##va.w,                    \
                   B##vb.x, B##vb.y, B##vb.z, B##vb.w};                   \
    _Pragma("unroll")                                                     \
    for (int i_ = 0; i_ < 8; i_++) ks[i_] += a_[i_];                      \
    _Pragma("unroll")                                                     \
    for (int i_ = 0; i_ < 8; i_++)                                        \
        _Pragma("unroll")                                                 \
        for (int j_ = 0; j_ < 8; j_++)                                    \
            acc[i_][j_] = fmaf(a_[i_], b_[j_], acc[i_][j_]);              \
} while (0)

__global__ __launch_bounds__(512) void k_phase1(const float* __restrict__ Kin,
                                                const float* __restrict__ Vin,
                                                float* __restrict__ pKV,
                                                float* __restrict__ pKs,
                                                int NC, int sLen) {
    const int n  = blockIdx.x / NC;
    const int ck = blockIdx.x % NC;
    const int t  = threadIdx.x;
    const int h    = t >> 6;        // wave id = head
    const int lane = t & 63;
    const int d0 = (lane >> 3) * 8; // owned d block (8)
    const int v0 = (lane & 7) * 8;  // owned v block (8)

    float acc[8][8];
#pragma unroll
    for (int i = 0; i < 8; i++)
#pragma unroll
        for (int j = 0; j < 8; j++) acc[i][j] = 0.0f;
    float ks[8] = {0.f, 0.f, 0.f, 0.f, 0.f, 0.f, 0.f, 0.f};

    const int s0 = ck * sLen;
    const float* Kp = Kin + ((size_t)(n * SEQ + s0) * NH + h) * DIM;
    const float* Vp = Vin + ((size_t)(n * SEQ + s0) * NH + h) * DIM;

    float4 p0ka, p0kb, p0va, p0vb;
    float4 p1ka, p1kb, p1va, p1vb;
    float4 p2ka, p2kb, p2va, p2vb;
    float4 p3ka, p3kb, p3va, p3vb;

    // prologue: rows 0..3 in flight
    ROW_LOAD(p0, 0);
    ROW_LOAD(p1, 1);
    ROW_LOAD(p2, 2);
    ROW_LOAD(p3, 3);

    // main: compute row s, immediately refill its buffer with row s+4
    for (int s = 0; s < sLen - 4; s += 4) {
        ROW_COMPUTE(p0); ROW_LOAD(p0, s + 4);
        ROW_COMPUTE(p1); ROW_LOAD(p1, s + 5);
        ROW_COMPUTE(p2); ROW_LOAD(p2, s + 6);
        ROW_COMPUTE(p3); ROW_LOAD(p3, s + 7);
    }
    // epilogue: last 4 rows
    ROW_COMPUTE(p0);
    ROW_COMPUTE(p1);
    ROW_COMPUTE(p2);
    ROW_COMPUTE(p3);

    // store partial KV: pKV[(ck*32 + n*8+h)][d][v] — each wave a distinct slot
    const int nh = n * 8 + h;
    float* dst = pKV + ((size_t)ck * 32 + nh) * 4096;
#pragma unroll
    for (int i = 0; i < 8; i++) {
        float4 oa, ob;
        oa.x = acc[i][0]; oa.y = acc[i][1]; oa.z = acc[i][2]; oa.w = acc[i][3];
        ob.x = acc[i][4]; ob.y = acc[i][5]; ob.z = acc[i][6]; ob.w = acc[i][7];
        *(float4*)(dst + (d0 + i) * 64 + v0)     = oa;
        *(float4*)(dst + (d0 + i) * 64 + v0 + 4) = ob;
    }
    // Ksum: the 8 lanes sharing d0 hold identical ks; one lane per group writes
    if ((lane & 7) == 0) {
#pragma unroll
        for (int i = 0; i < 8; i++)
            pKs[((size_t)ck * 32 + nh) * 64 + d0 + i] = ks[i];
    }
}

// ---------------- Reduce partials -> final KV, Ksum ----------------
template <int NC>
__global__ __launch_bounds__(128) void k_reduceT(const float* __restrict__ pKV,
                                                 const float* __restrict__ pKs,
                                                 float* __restrict__ KVf,
                                                 float* __restrict__ Ksf) {
    const int gid = blockIdx.x * 128 + threadIdx.x;   // 0..32767, one float4 each
    const float4* p4 = (const float4*)pKV;
    float4 s = make_float4(0.f, 0.f, 0.f, 0.f);
#pragma unroll
    for (int c = 0; c < NC; ++c) {
        float4 v = p4[(size_t)c * 32768 + gid];
        s.x += v.x; s.y += v.y; s.z += v.z; s.w += v.w;
    }
    ((float4*)KVf)[gid] = s;
    if (gid < 2048) {
        float ss = 0.0f;
#pragma unroll
        for (int c = 0; c < NC; ++c) ss += pKs[(size_t)c * 2048 + gid];
        Ksf[gid] = ss;
    }
}

__global__ __launch_bounds__(128) void k_reduceG(const float* __restrict__ pKV,
                                                 const float* __restrict__ pKs,
                                                 float* __restrict__ KVf,
                                                 float* __restrict__ Ksf, int NC) {
    const int gid = blockIdx.x * 128 + threadIdx.x;
    const float4* p4 = (const float4*)pKV;
    float4 s = make_float4(0.f, 0.f, 0.f, 0.f);
    for (int c = 0; c < NC; ++c) {
        float4 v = p4[(size_t)c * 32768 + gid];
        s.x += v.x; s.y += v.y; s.z += v.z; s.w += v.w;
    }
    ((float4*)KVf)[gid] = s;
    if (gid < 2048) {
        float ss = 0.0f;
        for (int c = 0; c < NC; ++c) ss += pKs[(size_t)c * 2048 + gid];
        Ksf[gid] = ss;
    }
}

// ---------------- Phase 2: register-tiled GEMM, out[l,v] = (Qf.KV[:,v]) / (Qf.Ks + eps) ----------------
// (R4/R5-benched version, ~14.5us: 512 blocks, 8x8 per-thread tile, Qt chunked
// to 16 d-rows, swizzle col = row ^ (dl&12) -> <=2-way on writes and reads.)
__global__ __launch_bounds__(256) void k_phase2(const float* __restrict__ Qin,
                                                const float* __restrict__ KVf,
                                                const float* __restrict__ Ksf,
                                                float* __restrict__ Out) {
    const int nh   = blockIdx.x >> 4;
    const int tile = blockIdx.x & 15;
    const int n = nh >> 3, h = nh & 7;
    const int t = threadIdx.x;

    __shared__ __align__(16) float Qt[16 * 256];   // 16 KB, swizzled transpose chunk
    __shared__ __align__(16) float KVs[64][64];    // 16 KB
    __shared__ float Kss[64];

    // stage KV + Ksum (coalesced; small, L2/L3-resident)
    {
        const float4* src = (const float4*)(KVf + (size_t)nh * 4096);
        float4* dst = (float4*)&KVs[0][0];
#pragma unroll
        for (int i = 0; i < 4; ++i) dst[t + 256 * i] = src[t + 256 * i];
        if (t < 64) Kss[t] = Ksf[nh * 64 + t];
    }

    const int l0 = tile * 256;
    const int r0 = (t >> 3) * 8;     // owned rows (8), 0..248
    const int v0 = (t & 7) * 8;      // owned cols (8)

    float acc[8][8];
#pragma unroll
    for (int i = 0; i < 8; i++)
#pragma unroll
        for (int j = 0; j < 8; j++) acc[i][j] = 0.0f;
    float p[8] = {0.f, 0.f, 0.f, 0.f, 0.f, 0.f, 0.f, 0.f};

    for (int dc = 0; dc < 4; ++dc) {
        if (dc) __syncthreads();       // protect Qt before overwrite
        // stage Q chunk (16 d) transposed+swizzled: 1024 float4
#pragma unroll
        for (int i = 0; i < 4; ++i) {
            const int j   = t + 256 * i;
            const int row = j >> 2;           // 0..255
            const int dl4 = (j & 3) << 2;     // local d f4-group: 0,4,8,12
            const size_t g = ((size_t)(n * SEQ + l0 + row) * NH + h) * DIM + dc * 16 + dl4;
            float4 q4 = *(const float4*)(Qin + g);
            const int col = row ^ dl4;
            Qt[(dl4 + 0) * 256 + col] = elu1(q4.x);
            Qt[(dl4 + 1) * 256 + col] = elu1(q4.y);
            Qt[(dl4 + 2) * 256 + col] = elu1(q4.z);
            Qt[(dl4 + 3) * 256 + col] = elu1(q4.w);
        }
        __syncthreads();

#pragma unroll 2
        for (int dl = 0; dl < 16; ++dl) {
            const int d = dc * 16 + dl;
            const int s = dl & 12;
            float4 qa = *(const float4*)&Qt[dl * 256 + (r0 ^ s)];
            float4 qb = *(const float4*)&Qt[dl * 256 + ((r0 + 4) ^ s)];
            float4 ka = *(const float4*)&KVs[d][v0];
            float4 kb = *(const float4*)&KVs[d][v0 + 4];
            const float ksd = Kss[d];
            float q[8]  = {qa.x, qa.y, qa.z, qa.w, qb.x, qb.y, qb.z, qb.w};
            float kv[8] = {ka.x, ka.y, ka.z, ka.w, kb.x, kb.y, kb.z, kb.w};
#pragma unroll
            for (int i = 0; i < 8; ++i) {
                p[i] = fmaf(q[i], ksd, p[i]);
#pragma unroll
                for (int jj = 0; jj < 8; ++jj)
                    acc[i][jj] = fmaf(q[i], kv[jj], acc[i][jj]);
            }
        }
    }

    // epilogue: scale by 1/(p+eps), float4 stores
#pragma unroll
    for (int i = 0; i < 8; ++i) {
        const float z = 1.0f / (p[i] + 1e-6f);
        const int l = l0 + r0 + i;
        float* o = Out + ((size_t)(n * SEQ + l) * NH + h) * DIM + v0;
        float4 oa, ob;
        oa.x = acc[i][0] * z; oa.y = acc[i][1] * z; oa.z = acc[i][2] * z; oa.w = acc[i][3] * z;
        ob.x = acc[i][4] * z; ob.y = acc[i][5] * z; ob.z = acc[i][6] * z; ob.w = acc[i][7] * z;
        *(float4*)(o)     = oa;
        *(float4*)(o + 4) = ob;
    }
}

extern "C" void kernel_launch(void* const* d_in, const int* in_sizes, int n_in,
                              void* d_out, int out_size, void* d_ws, size_t ws_size,
                              hipStream_t stream) {
    const float* Q = (const float*)d_in[0];
    const float* K = (const float*)d_in[1];
    const float* V = (const float*)d_in[2];
    float* out = (float*)d_out;

    // ws layout: [KVf 32*4096][Ksf 32*64][pKV NC*32*4096][pKs NC*32*64]
    int NC = 64;  // grid = 4n * NC = 256 blocks of 512 thr -> all CUs busy
    const size_t unit = 133120ull * 4ull; // (4096+64)*32 floats in bytes
    while (NC > 1 && (size_t)(NC + 1) * unit > ws_size) NC >>= 1;
    const int sLen = SEQ / NC;

    float* KVf = (float*)d_ws;
    float* Ksf = KVf + 32 * 4096;
    float* pKV = Ksf + 32 * 64;
    float* pKs = pKV + (size_t)NC * 32 * 4096;

    hipLaunchKernelGGL(k_phase1, dim3(4 * NC), dim3(512), 0, stream, K, V, pKV, pKs, NC, sLen);
    switch (NC) {
        case 64: hipLaunchKernelGGL(k_reduceT<64>, dim3(256), dim3(128), 0, stream, pKV, pKs, KVf, Ksf); break;
        case 32: hipLaunchKernelGGL(k_reduceT<32>, dim3(256), dim3(128), 0, stream, pKV, pKs, KVf, Ksf); break;
        case 16: hipLaunchKernelGGL(k_reduceT<16>, dim3(256), dim3(128), 0, stream, pKV, pKs, KVf, Ksf); break;
        case 8:  hipLaunchKernelGGL(k_reduceT<8>,  dim3(256), dim3(128), 0, stream, pKV, pKs, KVf, Ksf); break;
        default: hipLaunchKernelGGL(k_reduceG, dim3(256), dim3(128), 0, stream, pKV, pKs, KVf, Ksf, NC); break;
    }
    hipLaunchKernelGGL(k_phase2, dim3(512), dim3(256), 0, stream, Q, KVf, Ksf, out);
}